// Round 9
// baseline (1678.406 us; speedup 1.0000x reference)
//
#include <hip/hip_runtime.h>
#include <math.h>

constexpr int V = 128;   // vocab (fixed for this instance)

// ---- DPP wave-wide shifts (VALU, no LDS pipe, no lgkm wait) ----
__device__ __forceinline__ double dpp_shr1_f64(double x) {
    int lo = __builtin_amdgcn_update_dpp(0, __double2loint(x), 0x138, 0xf, 0xf, false);
    int hi = __builtin_amdgcn_update_dpp(0, __double2hiint(x), 0x138, 0xf, 0xf, false);
    return __hiloint2double(hi, lo);
}
__device__ __forceinline__ double dpp_shl1_f64(double x) {
    int lo = __builtin_amdgcn_update_dpp(0, __double2loint(x), 0x130, 0xf, 0xf, false);
    int hi = __builtin_amdgcn_update_dpp(0, __double2hiint(x), 0x130, 0xf, 0xf, false);
    return __hiloint2double(hi, lo);
}

// ======================= PATH A: single fused kernel ========================
// Blocks [0, nPre): prelude role (4 waves, one row each):
//   z = lse(x), x0 = x[0], g[i] = exp(x[lab_i]-x0); release-count cnt[b].
// Blocks [nPre, nPre+2B): scan role (1 wave): acquire-spin on cnt[b]==T,
//   then f64 blank-factored scan (fwd or bwd half). fwd+bwd rendezvous on
//   done[b]; second arriver combines; last batch (gdone) writes the mean.
// f64 state is REQUIRED (r6: fp32's 88-nat window flushes junction slots).
// Scan is f64-issue-bound: 21 f64-pipe ops x 8 cyc = 168 ~= 172 measured (r8).
__global__ __launch_bounds__(256) void ctc_fused(
    const float* __restrict__ pred,   // [B,T,V]
    const int*   __restrict__ plen,   // [B]
    const int*   __restrict__ gt,     // [B,S]
    const int*   __restrict__ glen,   // [B]
    int* cnt, int* done, int* gdone, float* lossb,
    float* __restrict__ g, float* __restrict__ z, float* __restrict__ x0a,
    double* __restrict__ fwdv, double* __restrict__ bwdv,
    int* __restrict__ Kf, int* __restrict__ Kb,
    float* __restrict__ out,
    int T, int S, int B, int nPre)
{
    __shared__ float rows[4][V];

    if ((int)blockIdx.x < nPre) {
        // ---------------- prelude role ----------------
        int wid  = blockIdx.x * 4 + (threadIdx.x >> 6);
        int lane = threadIdx.x & 63;
        int w4   = threadIdx.x >> 6;
        int b    = wid / T;
        int t    = wid - b * T;
        if (t >= plen[b]) {           // row never read downstream
            if (lane == 0)
                __hip_atomic_fetch_add(&cnt[b], 1, __ATOMIC_RELAXED,
                                       __HIP_MEMORY_SCOPE_AGENT);
            return;
        }
        const float2* p = (const float2*)pred + (size_t)wid * 64;
        float2 v = p[lane];
        rows[w4][2 * lane]     = v.x;
        rows[w4][2 * lane + 1] = v.y;
        float x0 = __shfl(v.x, 0, 64);
        float s = __expf(v.x) + __expf(v.y);
        #pragma unroll
        for (int off = 32; off >= 1; off >>= 1) s += __shfl_xor(s, off, 64);
        if (lane == 0) { z[wid] = __logf(s); x0a[wid] = v.x; }

        int4 la = *(const int4*)(gt + b * S + 4 * lane);
        int tl = glen[b];
        float4 o;
        o.x = (4 * lane + 0 < tl) ? __expf(rows[w4][la.x] - x0) : 0.f;
        o.y = (4 * lane + 1 < tl) ? __expf(rows[w4][la.y] - x0) : 0.f;
        o.z = (4 * lane + 2 < tl) ? __expf(rows[w4][la.z] - x0) : 0.f;
        o.w = (4 * lane + 3 < tl) ? __expf(rows[w4][la.w] - x0) : 0.f;
        *(float4*)(g + (size_t)wid * 256 + 4 * lane) = o;

        // release: s_waitcnt drains the WHOLE wave's stores before the add
        __threadfence();
        if (lane == 0)
            __hip_atomic_fetch_add(&cnt[b], 1, __ATOMIC_RELEASE,
                                   __HIP_MEMORY_SCOPE_AGENT);
        return;
    }

    // ---------------- scan role (1 wave; waves 1-3 exit) ----------------
    if (threadIdx.x >= 64) return;
    const int sblk = blockIdx.x - nPre;
    const int b    = sblk >> 1;
    const int dir  = sblk & 1;
    const int lane = threadIdx.x;

    {   // wait for this batch's prelude rows (bounded: no hang)
        long iter = 0;
        while (__hip_atomic_load(&cnt[b], __ATOMIC_ACQUIRE,
                                 __HIP_MEMORY_SCOPE_AGENT) < T) {
            __builtin_amdgcn_s_sleep(8);
            if (++iter > 200000000L) break;
        }
    }
    __threadfence();   // wave-wide invalidate before reading g/z/x0

    const int len = plen[b];
    const int tl  = glen[b];
    const int L   = 2 * tl + 1;
    const int m   = (len + 1) >> 1;

    int4 la = *(const int4*)(gt + b * S + 4 * lane);
    int law_up = __shfl_up(la.w, 1, 64);     // init-time only
    int lax_dn = __shfl_down(la.x, 1, 64);
    const double sk0 = (lane > 0 && la.x != law_up) ? 1.0 : 0.0;
    const double sk1 = (la.y != la.x) ? 1.0 : 0.0;
    const double sk2 = (la.z != la.y) ? 1.0 : 0.0;
    const double sk3 = (la.w != la.z) ? 1.0 : 0.0;
    const double sk4 = (lax_dn != la.w) ? 1.0 : 0.0;

    const char* gb = (const char*)(g + (size_t)b * T * 256) + lane * 16;

    float4 raw[16];
    double u[9];
    int K = 0;

    auto RESCALE = [&]() {
        double mx = u[0];
        #pragma unroll
        for (int j = 1; j < 9; ++j) mx = fmax(mx, u[j]);
        #pragma unroll
        for (int off = 32; off >= 1; off >>= 1)
            mx = fmax(mx, __shfl_xor(mx, off, 64));
        int k = ((__double2hiint(mx) >> 20) & 0x7ff) - 1023;
        #pragma unroll
        for (int j = 0; j < 9; ++j) u[j] = ldexp(u[j], -k);  // exact
        K += k;
    };

    if (dir == 0) {
        // forward
        #pragma unroll
        for (int i = 0; i < 16; ++i)
            raw[i] = *(const float4*)(gb + (size_t)i * 1024);
        #pragma unroll
        for (int j = 0; j < 9; ++j) u[j] = 0.0;
        if (lane == 0) { u[0] = 1.0; u[1] = (double)raw[0].x; }
        raw[0] = *(const float4*)(gb + (size_t)16 * 1024);
        const char* pf = gb + (size_t)17 * 1024;

        auto FSTEP = [&](int i) {   // i MUST be compile-time constant (r5)
            float4 g4 = raw[i];
            raw[i] = *(const float4*)pf; pf += 1024;
            double um1 = dpp_shr1_f64(u[7]);          // lane0 -> 0 (exact)
            double gx = (double)g4.x, gy = (double)g4.y;
            double gz = (double)g4.z, gw = (double)g4.w;
            u[8] = u[8] + u[7];
            u[7] = (fma(sk3, u[5], u[6]) + u[7]) * gw;
            u[6] = u[6] + u[5];
            u[5] = (fma(sk2, u[3], u[4]) + u[5]) * gz;
            u[4] = u[4] + u[3];
            u[3] = (fma(sk1, u[1], u[2]) + u[3]) * gy;
            u[2] = u[2] + u[1];
            u[1] = (fma(sk0, um1, u[0]) + u[1]) * gx;
            u[0] = u[0] + um1;
        };

        #pragma unroll
        for (int t = 1; t < 16; ++t) FSTEP(t);
        int tb = 16;
        for (; tb + 16 <= m; tb += 16) {
            #pragma unroll
            for (int i = 0; i < 16; ++i) FSTEP(i);
            if (((tb + 16) & 63) == 0) RESCALE();
        }
        #pragma unroll
        for (int i = 0; i < 15; ++i)
            if (tb + i < m) FSTEP(i);
        RESCALE();

        double* outv = fwdv + (size_t)b * 520;
        #pragma unroll
        for (int j = 0; j < 8; ++j) outv[8 * lane + j] = u[j];
        if (lane == 63) outv[512] = u[8];
        if (lane == 0)  Kf[b] = K;
    } else {
        // backward
        const int nb = len - m;
        #pragma unroll
        for (int i = 0; i < 16; ++i)
            raw[i] = *(const float4*)(gb + (size_t)(len - 1 - i) * 1024);
        #pragma unroll
        for (int j = 0; j < 8; ++j) {
            int s = 8 * lane + j;
            u[j] = (s == 2 * tl || s == 2 * tl - 1) ? 1.0 : 0.0;
        }
        u[8] = (L == 513) ? 1.0 : 0.0;
        const char* pf = gb + (size_t)(len - 17) * 1024;

        auto BSTEP = [&](int i) {   // i MUST be compile-time constant
            float4 g4 = raw[i];
            raw[i] = *(const float4*)pf; pf -= 1024;
            double d0 = dpp_shl1_f64(u[0]);
            if (lane == 63) d0 = u[8];
            double p1 = (double)g4.x * u[1], p3 = (double)g4.y * u[3];
            double p5 = (double)g4.z * u[5], p7 = (double)g4.w * u[7];
            double dp = dpp_shl1_f64(p1);             // lane63 -> 0
            u[0] = u[0] + p1;
            u[1] = fma(sk1, p3, u[2]) + p1;
            u[2] = u[2] + p3;
            u[3] = fma(sk2, p5, u[4]) + p3;
            u[4] = u[4] + p5;
            u[5] = fma(sk3, p7, u[6]) + p5;
            u[6] = u[6] + p7;
            u[7] = fma(sk4, dp, d0) + p7;
        };

        #pragma unroll
        for (int k = 0; k < 16; ++k) BSTEP(k);
        int kb = 16;
        for (; kb + 16 <= nb; kb += 16) {
            #pragma unroll
            for (int i = 0; i < 16; ++i) BSTEP(i);
            if (((kb + 16) & 63) == 0) RESCALE();
        }
        #pragma unroll
        for (int i = 0; i < 15; ++i)
            if (kb + i < nb) BSTEP(i);
        RESCALE();

        double* outv = bwdv + (size_t)b * 520;
        #pragma unroll
        for (int j = 0; j < 8; ++j) outv[8 * lane + j] = u[j];
        if (lane == 63) outv[512] = u[8];
        if (lane == 0)  Kb[b] = K;
    }

    // ---------------- rendezvous: second arriver combines ----------------
    __threadfence();
    int prev = 0;
    if (lane == 0)
        prev = __hip_atomic_fetch_add(&done[b], 1, __ATOMIC_ACQ_REL,
                                      __HIP_MEMORY_SCOPE_AGENT);
    prev = __shfl(prev, 0, 64);
    if (prev == 0) return;            // first arriver: done
    __threadfence();                  // see the other block's fwdv/bwdv/K

    const double* f = fwdv + (size_t)b * 520;
    const double* w = bwdv + (size_t)b * 520;
    double c = 0.0;
    #pragma unroll
    for (int j = 0; j < 8; ++j)
        c = fma(f[8 * lane + j], w[8 * lane + j], c);
    if (lane == 63) c = fma(f[512], w[512], c);
    #pragma unroll
    for (int off = 32; off >= 1; off >>= 1) c += __shfl_xor(c, off, 64);

    double zs = 0.0;
    for (int t = lane; t < len; t += 64)
        zs += (double)z[b * T + t] - (double)x0a[b * T + t];
    #pragma unroll
    for (int off = 32; off >= 1; off >>= 1) zs += __shfl_xor(zs, off, 64);

    if (lane == 0) {
        double logp = log(c)
                    + (double)(Kf[b] + Kb[b]) * 0.6931471805599453 - zs;
        double loss = -logp;
        if (!(loss < 1e10)) loss = 0.0;   // zero_infinity
        lossb[b] = (float)(loss / (double)tl);
        int pg = __hip_atomic_fetch_add(gdone, 1, __ATOMIC_ACQ_REL,
                                        __HIP_MEMORY_SCOPE_AGENT);
        if (pg == B - 1) {                // last batch: deterministic mean
            __threadfence();
            float ssum = 0.0f;
            for (int i = 0; i < B; ++i) ssum += lossb[i];
            out[0] = ssum / (float)B;
        }
    }
}

// ======================= PATH B (fallback: proven round-3) ==================
constexpr int SPL  = 9;
constexpr int RING = 32;

__global__ void ctc_reduce_kernel(const float* __restrict__ ls,
                                  float* __restrict__ out, int B)
{
    if (blockIdx.x == 0 && threadIdx.x == 0) {
        float s = 0.0f;
        for (int i = 0; i < B; ++i) s += ls[i];
        out[0] = s / (float)B;
    }
}

__global__ __launch_bounds__(256) void softmax_z_kernel(
    const float* __restrict__ pred, float* __restrict__ z, int nrows)
{
    int w    = blockIdx.x * 4 + (threadIdx.x >> 6);
    int lane = threadIdx.x & 63;
    if (w >= nrows) return;
    const float2* p = (const float2*)pred;
    float2 v = p[(size_t)w * 64 + lane];
    float s = __expf(v.x) + __expf(v.y);
    #pragma unroll
    for (int off = 32; off >= 1; off >>= 1) s += __shfl_xor(s, off, 64);
    if (lane == 0) z[w] = __logf(s);
}

__device__ __forceinline__ void ctc_step_fb(
    const float* __restrict__ rowbase, const int* __restrict__ goff,
    const double* __restrict__ skd, double (&u)[SPL], int lane)
{
    float gf[SPL];
    #pragma unroll
    for (int j = 0; j < SPL; ++j)
        gf[j] = *(const float*)((const char*)rowbase + goff[j]);
    double um1 = __shfl_up(u[8], 1, 64);
    double um2 = __shfl_up(u[7], 1, 64);
    if (lane == 0) { um1 = 0.0; um2 = 0.0; }
    #pragma unroll
    for (int jj = 0; jj < SPL; ++jj) {
        int j = SPL - 1 - jj;
        double a2 = (j >= 1) ? u[j - 1] : um1;
        double a3 = (j >= 2) ? u[j - 2] : ((j == 1) ? um1 : um2);
        double t  = fma(skd[j], a3, a2) + u[j];
        u[j] = t * (double)gf[j];
    }
}

__device__ __forceinline__ void ctc_rescale_fb(double (&u)[SPL], int& K)
{
    double m = u[0];
    #pragma unroll
    for (int j = 1; j < SPL; ++j) m = fmax(m, u[j]);
    #pragma unroll
    for (int off = 32; off >= 1; off >>= 1) m = fmax(m, __shfl_xor(m, off, 64));
    if (m > 0.0) {
        int e = (__double2hiint(m) >> 20) & 0x7ff;
        int k = e - 1023;
        #pragma unroll
        for (int j = 0; j < SPL; ++j) u[j] = ldexp(u[j], -k);
        K += k;
    }
}

__global__ __launch_bounds__(64) void ctc_scan_kernel(
    const float* __restrict__ pred, const int* __restrict__ pred_len,
    const int* __restrict__ gt, const int* __restrict__ gt_len,
    const float* __restrict__ z, float* __restrict__ loss_out, int T, int S)
{
    const int b    = blockIdx.x;
    const int lane = threadIdx.x;
    const int len  = pred_len[b];
    const int tl   = gt_len[b];
    const int L    = 2 * tl + 1;

    __shared__ float ring[RING][V];
    __shared__ int   gts[512];

    for (int i = lane; i < S; i += 64) gts[i] = gt[b * S + i];
    __syncthreads();

    int    goff[SPL];
    double skd[SPL];
    #pragma unroll
    for (int j = 0; j < SPL; ++j) {
        int s = SPL * lane + j;
        int e = 0, ep = 0;
        if (s < L && (s & 1)) e = gts[s >> 1];
        if (s >= 2 && s < L && (s & 1)) ep = gts[(s - 2) >> 1];
        goff[j] = e * 4;
        skd[j]  = (s >= 2 && s < L && e != 0 && e != ep) ? 1.0 : 0.0;
    }

    const float2* rowp = (const float2*)(pred + (size_t)b * T * V);
    float2 raw[16];

    #pragma unroll
    for (int i = 0; i < 16; ++i) raw[i] = rowp[(size_t)i * 64 + lane];
    #pragma unroll
    for (int i = 0; i < 16; ++i) {
        float2 w; w.x = __expf(raw[i].x); w.y = __expf(raw[i].y);
        *(float2*)&ring[i][2 * lane] = w;
    }
    #pragma unroll
    for (int i = 0; i < 16; ++i) raw[i] = rowp[(size_t)(16 + i) * 64 + lane];
    #pragma unroll
    for (int i = 0; i < 16; ++i) {
        float2 w; w.x = __expf(raw[i].x); w.y = __expf(raw[i].y);
        *(float2*)&ring[16 + i][2 * lane] = w;
    }
    #pragma unroll
    for (int i = 0; i < 16; ++i) {
        int r = 32 + i; if (r > T - 1) r = T - 1;
        raw[i] = rowp[(size_t)r * 64 + lane];
    }

    double u[SPL];
    #pragma unroll
    for (int j = 0; j < SPL; ++j) {
        int s = SPL * lane + j;
        float w0 = *(const float*)((const char*)&ring[0][0] + goff[j]);
        u[j] = (s < 2) ? (double)w0 : 0.0;
    }
    int K = 0;

    for (int t = 1; t < 16 && t < len; ++t)
        ctc_step_fb(&ring[t & (RING - 1)][0], goff, skd, u, lane);
    ctc_rescale_fb(u, K);

    int tb = 16;
    for (; tb + 16 <= len; tb += 16) {
        #pragma unroll
        for (int i = 0; i < 16; ++i) {
            float2 w; w.x = __expf(raw[i].x); w.y = __expf(raw[i].y);
            *(float2*)&ring[(tb + 16 + i) & (RING - 1)][2 * lane] = w;
        }
        #pragma unroll
        for (int i = 0; i < 16; ++i) {
            int r = tb + 32 + i; if (r > T - 1) r = T - 1;
            raw[i] = rowp[(size_t)r * 64 + lane];
        }
        #pragma unroll
        for (int i = 0; i < 16; ++i)
            ctc_step_fb(&ring[(tb + i) & (RING - 1)][0], goff, skd, u, lane);
        ctc_rescale_fb(u, K);
    }

    for (int t = tb; t < len; ++t)
        ctc_step_fb(&ring[t & (RING - 1)][0], goff, skd, u, lane);

    double contrib = 0.0;
    #pragma unroll
    for (int j = 0; j < SPL; ++j) {
        int s = SPL * lane + j;
        if (s == L - 1 || s == L - 2) contrib += u[j];
    }
    #pragma unroll
    for (int off = 32; off >= 1; off >>= 1)
        contrib += __shfl_xor(contrib, off, 64);

    double zsum = 0.0;
    for (int t = lane; t < len; t += 64) zsum += (double)z[b * T + t];
    #pragma unroll
    for (int off = 32; off >= 1; off >>= 1)
        zsum += __shfl_xor(zsum, off, 64);

    if (lane == 0) {
        double lg    = log(contrib);
        double alpha = lg + (double)K * 0.6931471805599453 - zsum;
        double loss  = -alpha;
        if (!(loss < 1e10)) loss = 0.0;
        loss_out[b] = (float)(loss / (double)tl);
    }
}

// ======================= host =======================
extern "C" void kernel_launch(void* const* d_in, const int* in_sizes, int n_in,
                              void* d_out, int out_size, void* d_ws, size_t ws_size,
                              hipStream_t stream) {
    const float* pred = (const float*)d_in[0];   // [B, T, V] fp32
    const int*   plen = (const int*)d_in[1];     // [B]
    const int*   gts  = (const int*)d_in[2];     // [B, S]
    const int*   glen = (const int*)d_in[3];     // [B]

    const int B = in_sizes[1];
    const int S = in_sizes[2] / B;
    const int T = in_sizes[0] / (B * V);
    const size_t BT = (size_t)B * T;

    float* out = (float*)d_out;
    char*  ws  = (char*)d_ws;

    // fast-path workspace layout (8-aligned by construction)
    size_t off_fl  = 0;                              // flags: 1024 B
    size_t off_z   = 1024;
    size_t off_x0  = off_z   + BT * 4;
    size_t off_fw  = (off_x0 + BT * 4 + 255) & ~(size_t)255;
    size_t off_bw  = off_fw  + (size_t)B * 520 * 8;
    size_t off_kf  = off_bw  + (size_t)B * 520 * 8;
    size_t off_kb  = off_kf  + (size_t)B * 4;
    size_t off_g   = (off_kb + (size_t)B * 4 + 1023) & ~(size_t)1023;
    size_t need    = off_g + BT * 256 * 4;

    bool fast_ok = (ws_size >= need) && (S == 256) && (T % 4 == 0) &&
                   (T >= 96) && (B >= 1) && (B <= 64);

    if (fast_ok) {
        int*    cnt   = (int*)(ws + off_fl);          // [64]
        int*    done  = (int*)(ws + off_fl + 256);    // [64]
        int*    gdone = (int*)(ws + off_fl + 512);    // [1]
        float*  lossb = (float*)(ws + off_fl + 768);  // [64]
        float*  zp    = (float*)(ws + off_z);
        float*  x0a   = (float*)(ws + off_x0);
        double* fw    = (double*)(ws + off_fw);
        double* bw    = (double*)(ws + off_bw);
        int*    kf    = (int*)(ws + off_kf);
        int*    kb    = (int*)(ws + off_kb);
        float*  g     = (float*)(ws + off_g);

        int nPre = B * T / 4;
        hipMemsetAsync(ws + off_fl, 0, 768, stream);  // cnt/done/gdone
        ctc_fused<<<nPre + 2 * B, 256, 0, stream>>>(
            pred, plen, gts, glen, cnt, done, gdone, lossb,
            g, zp, x0a, fw, bw, kf, kb, out, T, S, B, nPre);
    } else {
        float* zbuf = (float*)ws;                 // B*T
        float* lb   = zbuf + BT;                  // B
        int nrows = B * T;
        softmax_z_kernel<<<(nrows + 3) / 4, 256, 0, stream>>>(pred, zbuf, nrows);
        ctc_scan_kernel<<<B, 64, 0, stream>>>(pred, plen, gts, glen, zbuf, lb, T, S);
        ctc_reduce_kernel<<<1, 64, 0, stream>>>(lb, out, B);
    }
}

// Round 10
// 173.384 us; speedup vs baseline: 9.6803x; 9.6803x over previous
//
#include <hip/hip_runtime.h>
#include <math.h>

constexpr int V = 128;   // vocab (fixed for this instance)

// ---- DPP wave-wide shifts (VALU, no LDS pipe, no lgkm wait) ----
__device__ __forceinline__ double dpp_shr1_f64(double x) {
    int lo = __builtin_amdgcn_update_dpp(0, __double2loint(x), 0x138, 0xf, 0xf, false);
    int hi = __builtin_amdgcn_update_dpp(0, __double2hiint(x), 0x138, 0xf, 0xf, false);
    return __hiloint2double(hi, lo);
}
__device__ __forceinline__ double dpp_shl1_f64(double x) {
    int lo = __builtin_amdgcn_update_dpp(0, __double2loint(x), 0x130, 0xf, 0xf, false);
    int hi = __builtin_amdgcn_update_dpp(0, __double2hiint(x), 0x130, 0xf, 0xf, false);
    return __hiloint2double(hi, lo);
}

// ======================= PATH A (r8 structure + fused epilogue) =============
// r9 LESSON: producer->consumer spin inside one grid thrashes L2 (WRITE_SIZE
// 55 MB, 10x regression). Keep the launch boundary between prelude and scan.
// f64 state REQUIRED (r6). Scan is f64-issue-bound (~21 f64 ops x 8 cyc, r8).
__global__ __launch_bounds__(256) void ctc_prelude(
    const float* __restrict__ pred, const int* __restrict__ gt,
    const int* __restrict__ gt_len, const int* __restrict__ pred_len,
    float* __restrict__ g, float* __restrict__ z, float* __restrict__ x0a,
    int T, int S)
{
    int wid  = blockIdx.x * 4 + (threadIdx.x >> 6);
    int lane = threadIdx.x & 63;
    int w4   = threadIdx.x >> 6;
    int b    = wid / T;
    int t    = wid - b * T;
    if (t >= pred_len[b]) return;     // wave-uniform: rows beyond len unread
    __shared__ float rows[4][V];      // wave-private regions: no barrier

    const float2* p = (const float2*)pred + (size_t)wid * 64;
    float2 v = p[lane];
    rows[w4][2 * lane]     = v.x;
    rows[w4][2 * lane + 1] = v.y;
    float x0 = __shfl(v.x, 0, 64);
    float s = __expf(v.x) + __expf(v.y);
    #pragma unroll
    for (int off = 32; off >= 1; off >>= 1) s += __shfl_xor(s, off, 64);
    if (lane == 0) { z[wid] = __logf(s); x0a[wid] = v.x; }

    int4 la = *(const int4*)(gt + b * S + 4 * lane);
    int tl = gt_len[b];
    float4 o;
    o.x = (4 * lane + 0 < tl) ? __expf(rows[w4][la.x] - x0) : 0.f;
    o.y = (4 * lane + 1 < tl) ? __expf(rows[w4][la.y] - x0) : 0.f;
    o.z = (4 * lane + 2 < tl) ? __expf(rows[w4][la.z] - x0) : 0.f;
    o.w = (4 * lane + 3 < tl) ? __expf(rows[w4][la.w] - x0) : 0.f;
    *(float4*)(g + (size_t)wid * 256 + 4 * lane) = o;
}

// Scan (2B blocks, 1 wave each) + fused no-spin epilogue:
// each block finishes its half-scan, then atomically bumps done[b]; the
// SECOND arriver (both halves written) does the junction dot + loss; the
// LAST batch (gdone) writes the batch mean. No block ever waits idle.
__global__ __launch_bounds__(64) void ctc_scan_bi(
    const float* __restrict__ g,
    const int*   __restrict__ pred_len,
    const int*   __restrict__ gt,
    const int*   __restrict__ gt_len,
    const float* __restrict__ z,
    const float* __restrict__ x0a,
    double*      __restrict__ fwdv,   // [B,520]
    double*      __restrict__ bwdv,   // [B,520]
    int*         __restrict__ Kf,     // [B]
    int*         __restrict__ Kb,     // [B]
    int* done, int* gdone, float* lossb,
    float* __restrict__ out,
    int T, int S, int B)
{
    const int blk  = blockIdx.x;
    const int b    = blk >> 1;
    const int dir  = blk & 1;
    const int lane = threadIdx.x;
    const int len  = pred_len[b];     // host guards T>=96 -> len>=48
    const int tl   = gt_len[b];
    const int L    = 2 * tl + 1;
    const int m    = (len + 1) >> 1;  // forward frames; backward nb = len-m

    int4 la = *(const int4*)(gt + b * S + 4 * lane);
    int law_up = __shfl_up(la.w, 1, 64);     // init-time only: DS ok here
    int lax_dn = __shfl_down(la.x, 1, 64);
    const double sk0 = (lane > 0 && la.x != law_up) ? 1.0 : 0.0; // skip[8i+1]
    const double sk1 = (la.y != la.x) ? 1.0 : 0.0;               // skip[8i+3]
    const double sk2 = (la.z != la.y) ? 1.0 : 0.0;               // skip[8i+5]
    const double sk3 = (la.w != la.z) ? 1.0 : 0.0;               // skip[8i+7]
    const double sk4 = (lax_dn != la.w) ? 1.0 : 0.0;             // skip[8i+9]

    const char* gb = (const char*)(g + (size_t)b * T * 256) + lane * 16;

    float4 raw[16];
    double u[9];
    int K = 0;

    auto RESCALE = [&]() {
        double mx = u[0];
        #pragma unroll
        for (int j = 1; j < 9; ++j) mx = fmax(mx, u[j]);
        #pragma unroll
        for (int off = 32; off >= 1; off >>= 1)
            mx = fmax(mx, __shfl_xor(mx, off, 64));
        int k = ((__double2hiint(mx) >> 20) & 0x7ff) - 1023;
        #pragma unroll
        for (int j = 0; j < 9; ++j) u[j] = ldexp(u[j], -k);  // exact
        K += k;
    };

    if (dir == 0) {
        // ---------------- forward ----------------
        #pragma unroll
        for (int i = 0; i < 16; ++i)
            raw[i] = *(const float4*)(gb + (size_t)i * 1024);
        #pragma unroll
        for (int j = 0; j < 9; ++j) u[j] = 0.0;
        if (lane == 0) { u[0] = 1.0; u[1] = (double)raw[0].x; }
        raw[0] = *(const float4*)(gb + (size_t)16 * 1024);
        const char* pf = gb + (size_t)17 * 1024;

        auto FSTEP = [&](int i) {   // i MUST be compile-time constant (r5)
            float4 g4 = raw[i];
            raw[i] = *(const float4*)pf; pf += 1024;  // issue prefetch early
            double um1 = dpp_shr1_f64(u[7]);          // lane0 -> 0 (exact)
            double gx = (double)g4.x, gy = (double)g4.y;
            double gz = (double)g4.z, gw = (double)g4.w;
            u[8] = u[8] + u[7];
            u[7] = (fma(sk3, u[5], u[6]) + u[7]) * gw;
            u[6] = u[6] + u[5];
            u[5] = (fma(sk2, u[3], u[4]) + u[5]) * gz;
            u[4] = u[4] + u[3];
            u[3] = (fma(sk1, u[1], u[2]) + u[3]) * gy;
            u[2] = u[2] + u[1];
            u[1] = (fma(sk0, um1, u[0]) + u[1]) * gx;
            u[0] = u[0] + um1;
        };

        #pragma unroll
        for (int t = 1; t < 16; ++t) FSTEP(t);
        int tb = 16;
        for (; tb + 16 <= m; tb += 16) {
            #pragma unroll
            for (int i = 0; i < 16; ++i) FSTEP(i);
            if (((tb + 16) & 63) == 0) RESCALE();
        }
        #pragma unroll
        for (int i = 0; i < 15; ++i)
            if (tb + i < m) FSTEP(i);
        RESCALE();   // normalize before junction product

        double* outv = fwdv + (size_t)b * 520;
        #pragma unroll
        for (int j = 0; j < 8; ++j) outv[8 * lane + j] = u[j];
        if (lane == 63) outv[512] = u[8];
        if (lane == 0)  Kf[b] = K;
    } else {
        // ---------------- backward ----------------
        const int nb = len - m;      // >= 23 for len >= 48
        #pragma unroll
        for (int i = 0; i < 16; ++i)
            raw[i] = *(const float4*)(gb + (size_t)(len - 1 - i) * 1024);
        #pragma unroll
        for (int j = 0; j < 8; ++j) {
            int s = 8 * lane + j;
            u[j] = (s == 2 * tl || s == 2 * tl - 1) ? 1.0 : 0.0;
        }
        u[8] = (L == 513) ? 1.0 : 0.0;   // slot 512 (lane 63's)
        const char* pf = gb + (size_t)(len - 17) * 1024;

        auto BSTEP = [&](int i) {   // i MUST be compile-time constant
            float4 g4 = raw[i];
            raw[i] = *(const float4*)pf; pf -= 1024;  // issue prefetch early
            double d0 = dpp_shl1_f64(u[0]);           // slot 8i+8 (pre-step)
            if (lane == 63) d0 = u[8];
            double p1 = (double)g4.x * u[1], p3 = (double)g4.y * u[3];
            double p5 = (double)g4.z * u[5], p7 = (double)g4.w * u[7];
            double dp = dpp_shl1_f64(p1);             // lane63 -> 0
            u[0] = u[0] + p1;
            u[1] = fma(sk1, p3, u[2]) + p1;
            u[2] = u[2] + p3;
            u[3] = fma(sk2, p5, u[4]) + p3;
            u[4] = u[4] + p5;
            u[5] = fma(sk3, p7, u[6]) + p5;
            u[6] = u[6] + p7;
            u[7] = fma(sk4, dp, d0) + p7;
        };

        #pragma unroll
        for (int k = 0; k < 16; ++k) BSTEP(k);
        int kb = 16;
        for (; kb + 16 <= nb; kb += 16) {
            #pragma unroll
            for (int i = 0; i < 16; ++i) BSTEP(i);
            if (((kb + 16) & 63) == 0) RESCALE();
        }
        #pragma unroll
        for (int i = 0; i < 15; ++i)
            if (kb + i < nb) BSTEP(i);
        RESCALE();

        double* outv = bwdv + (size_t)b * 520;
        #pragma unroll
        for (int j = 0; j < 8; ++j) outv[8 * lane + j] = u[j];
        if (lane == 63) outv[512] = u[8];
        if (lane == 0)  Kb[b] = K;
    }

    // -------- no-spin rendezvous: second arriver combines (r9-verified) ----
    __threadfence();
    int prev = 0;
    if (lane == 0)
        prev = __hip_atomic_fetch_add(&done[b], 1, __ATOMIC_ACQ_REL,
                                      __HIP_MEMORY_SCOPE_AGENT);
    prev = __shfl(prev, 0, 64);
    if (prev == 0) return;            // first arriver: exit immediately
    __threadfence();                  // acquire the other block's stores

    const double* f = fwdv + (size_t)b * 520;
    const double* w = bwdv + (size_t)b * 520;
    double c = 0.0;
    #pragma unroll
    for (int j = 0; j < 8; ++j)
        c = fma(f[8 * lane + j], w[8 * lane + j], c);
    if (lane == 63) c = fma(f[512], w[512], c);
    #pragma unroll
    for (int off = 32; off >= 1; off >>= 1) c += __shfl_xor(c, off, 64);

    double zs = 0.0;   // sum over t<len of (z_t - x0_t)
    for (int t = lane; t < len; t += 64)
        zs += (double)z[b * T + t] - (double)x0a[b * T + t];
    #pragma unroll
    for (int off = 32; off >= 1; off >>= 1) zs += __shfl_xor(zs, off, 64);

    if (lane == 0) {
        double logp = log(c)
                    + (double)(Kf[b] + Kb[b]) * 0.6931471805599453 - zs;
        double loss = -logp;
        if (!(loss < 1e10)) loss = 0.0;   // zero_infinity
        lossb[b] = (float)(loss / (double)tl);
        __threadfence();
        int pg = __hip_atomic_fetch_add(gdone, 1, __ATOMIC_ACQ_REL,
                                        __HIP_MEMORY_SCOPE_AGENT);
        if (pg == B - 1) {                // last batch: deterministic mean
            __threadfence();
            float ssum = 0.0f;
            for (int i = 0; i < B; ++i) ssum += lossb[i];
            out[0] = ssum / (float)B;
        }
    }
}

// ======================= PATH B (fallback: proven round-3) ==================
constexpr int SPL  = 9;
constexpr int RING = 32;

__global__ void ctc_reduce_kernel(const float* __restrict__ ls,
                                  float* __restrict__ out, int B)
{
    if (blockIdx.x == 0 && threadIdx.x == 0) {
        float s = 0.0f;
        for (int i = 0; i < B; ++i) s += ls[i];
        out[0] = s / (float)B;
    }
}

__global__ __launch_bounds__(256) void softmax_z_kernel(
    const float* __restrict__ pred, float* __restrict__ z, int nrows)
{
    int w    = blockIdx.x * 4 + (threadIdx.x >> 6);
    int lane = threadIdx.x & 63;
    if (w >= nrows) return;
    const float2* p = (const float2*)pred;
    float2 v = p[(size_t)w * 64 + lane];
    float s = __expf(v.x) + __expf(v.y);
    #pragma unroll
    for (int off = 32; off >= 1; off >>= 1) s += __shfl_xor(s, off, 64);
    if (lane == 0) z[w] = __logf(s);
}

__device__ __forceinline__ void ctc_step_fb(
    const float* __restrict__ rowbase, const int* __restrict__ goff,
    const double* __restrict__ skd, double (&u)[SPL], int lane)
{
    float gf[SPL];
    #pragma unroll
    for (int j = 0; j < SPL; ++j)
        gf[j] = *(const float*)((const char*)rowbase + goff[j]);
    double um1 = __shfl_up(u[8], 1, 64);
    double um2 = __shfl_up(u[7], 1, 64);
    if (lane == 0) { um1 = 0.0; um2 = 0.0; }
    #pragma unroll
    for (int jj = 0; jj < SPL; ++jj) {
        int j = SPL - 1 - jj;
        double a2 = (j >= 1) ? u[j - 1] : um1;
        double a3 = (j >= 2) ? u[j - 2] : ((j == 1) ? um1 : um2);
        double t  = fma(skd[j], a3, a2) + u[j];
        u[j] = t * (double)gf[j];
    }
}

__device__ __forceinline__ void ctc_rescale_fb(double (&u)[SPL], int& K)
{
    double m = u[0];
    #pragma unroll
    for (int j = 1; j < SPL; ++j) m = fmax(m, u[j]);
    #pragma unroll
    for (int off = 32; off >= 1; off >>= 1) m = fmax(m, __shfl_xor(m, off, 64));
    if (m > 0.0) {
        int e = (__double2hiint(m) >> 20) & 0x7ff;
        int k = e - 1023;
        #pragma unroll
        for (int j = 0; j < SPL; ++j) u[j] = ldexp(u[j], -k);
        K += k;
    }
}

__global__ __launch_bounds__(64) void ctc_scan_kernel(
    const float* __restrict__ pred, const int* __restrict__ pred_len,
    const int* __restrict__ gt, const int* __restrict__ gt_len,
    const float* __restrict__ z, float* __restrict__ loss_out, int T, int S)
{
    const int b    = blockIdx.x;
    const int lane = threadIdx.x;
    const int len  = pred_len[b];
    const int tl   = gt_len[b];
    const int L    = 2 * tl + 1;

    __shared__ float ring[RING][V];
    __shared__ int   gts[512];

    for (int i = lane; i < S; i += 64) gts[i] = gt[b * S + i];
    __syncthreads();

    int    goff[SPL];
    double skd[SPL];
    #pragma unroll
    for (int j = 0; j < SPL; ++j) {
        int s = SPL * lane + j;
        int e = 0, ep = 0;
        if (s < L && (s & 1)) e = gts[s >> 1];
        if (s >= 2 && s < L && (s & 1)) ep = gts[(s - 2) >> 1];
        goff[j] = e * 4;
        skd[j]  = (s >= 2 && s < L && e != 0 && e != ep) ? 1.0 : 0.0;
    }

    const float2* rowp = (const float2*)(pred + (size_t)b * T * V);
    float2 raw[16];

    #pragma unroll
    for (int i = 0; i < 16; ++i) raw[i] = rowp[(size_t)i * 64 + lane];
    #pragma unroll
    for (int i = 0; i < 16; ++i) {
        float2 w; w.x = __expf(raw[i].x); w.y = __expf(raw[i].y);
        *(float2*)&ring[i][2 * lane] = w;
    }
    #pragma unroll
    for (int i = 0; i < 16; ++i) raw[i] = rowp[(size_t)(16 + i) * 64 + lane];
    #pragma unroll
    for (int i = 0; i < 16; ++i) {
        float2 w; w.x = __expf(raw[i].x); w.y = __expf(raw[i].y);
        *(float2*)&ring[16 + i][2 * lane] = w;
    }
    #pragma unroll
    for (int i = 0; i < 16; ++i) {
        int r = 32 + i; if (r > T - 1) r = T - 1;
        raw[i] = rowp[(size_t)r * 64 + lane];
    }

    double u[SPL];
    #pragma unroll
    for (int j = 0; j < SPL; ++j) {
        int s = SPL * lane + j;
        float w0 = *(const float*)((const char*)&ring[0][0] + goff[j]);
        u[j] = (s < 2) ? (double)w0 : 0.0;
    }
    int K = 0;

    for (int t = 1; t < 16 && t < len; ++t)
        ctc_step_fb(&ring[t & (RING - 1)][0], goff, skd, u, lane);
    ctc_rescale_fb(u, K);

    int tb = 16;
    for (; tb + 16 <= len; tb += 16) {
        #pragma unroll
        for (int i = 0; i < 16; ++i) {
            float2 w; w.x = __expf(raw[i].x); w.y = __expf(raw[i].y);
            *(float2*)&ring[(tb + 16 + i) & (RING - 1)][2 * lane] = w;
        }
        #pragma unroll
        for (int i = 0; i < 16; ++i) {
            int r = tb + 32 + i; if (r > T - 1) r = T - 1;
            raw[i] = rowp[(size_t)r * 64 + lane];
        }
        #pragma unroll
        for (int i = 0; i < 16; ++i)
            ctc_step_fb(&ring[(tb + i) & (RING - 1)][0], goff, skd, u, lane);
        ctc_rescale_fb(u, K);
    }

    for (int t = tb; t < len; ++t)
        ctc_step_fb(&ring[t & (RING - 1)][0], goff, skd, u, lane);

    double contrib = 0.0;
    #pragma unroll
    for (int j = 0; j < SPL; ++j) {
        int s = SPL * lane + j;
        if (s == L - 1 || s == L - 2) contrib += u[j];
    }
    #pragma unroll
    for (int off = 32; off >= 1; off >>= 1)
        contrib += __shfl_xor(contrib, off, 64);

    double zsum = 0.0;
    for (int t = lane; t < len; t += 64) zsum += (double)z[b * T + t];
    #pragma unroll
    for (int off = 32; off >= 1; off >>= 1)
        zsum += __shfl_xor(zsum, off, 64);

    if (lane == 0) {
        double lg    = log(contrib);
        double alpha = lg + (double)K * 0.6931471805599453 - zsum;
        double loss  = -alpha;
        if (!(loss < 1e10)) loss = 0.0;
        loss_out[b] = (float)(loss / (double)tl);
    }
}

// ======================= host =======================
extern "C" void kernel_launch(void* const* d_in, const int* in_sizes, int n_in,
                              void* d_out, int out_size, void* d_ws, size_t ws_size,
                              hipStream_t stream) {
    const float* pred = (const float*)d_in[0];   // [B, T, V] fp32
    const int*   plen = (const int*)d_in[1];     // [B]
    const int*   gts  = (const int*)d_in[2];     // [B, S]
    const int*   glen = (const int*)d_in[3];     // [B]

    const int B = in_sizes[1];
    const int S = in_sizes[2] / B;
    const int T = in_sizes[0] / (B * V);
    const size_t BT = (size_t)B * T;

    float* out = (float*)d_out;
    char*  ws  = (char*)d_ws;

    // fast-path workspace layout (8-aligned by construction)
    size_t off_fl  = 0;                              // flags: 1024 B
    size_t off_z   = 1024;
    size_t off_x0  = off_z   + BT * 4;
    size_t off_fw  = (off_x0 + BT * 4 + 255) & ~(size_t)255;
    size_t off_bw  = off_fw  + (size_t)B * 520 * 8;
    size_t off_kf  = off_bw  + (size_t)B * 520 * 8;
    size_t off_kb  = off_kf  + (size_t)B * 4;
    size_t off_g   = (off_kb + (size_t)B * 4 + 1023) & ~(size_t)1023;
    size_t need    = off_g + BT * 256 * 4;

    bool fast_ok = (ws_size >= need) && (S == 256) && (T % 4 == 0) &&
                   (T >= 96) && (B >= 1) && (B <= 64);

    if (fast_ok) {
        int*    done  = (int*)(ws + off_fl);          // [64]
        int*    gdone = (int*)(ws + off_fl + 256);    // [1]
        float*  lossb = (float*)(ws + off_fl + 512);  // [64]
        float*  zp    = (float*)(ws + off_z);
        float*  x0a   = (float*)(ws + off_x0);
        double* fw    = (double*)(ws + off_fw);
        double* bw    = (double*)(ws + off_bw);
        int*    kf    = (int*)(ws + off_kf);
        int*    kb    = (int*)(ws + off_kb);
        float*  g     = (float*)(ws + off_g);

        hipMemsetAsync(ws + off_fl, 0, 512, stream);  // done/gdone
        ctc_prelude<<<B * T / 4, 256, 0, stream>>>(pred, gts, glen, plen,
                                                   g, zp, x0a, T, S);
        ctc_scan_bi<<<2 * B, 64, 0, stream>>>(g, plen, gts, glen, zp, x0a,
                                              fw, bw, kf, kb,
                                              done, gdone, lossb, out, T, S, B);
    } else {
        float* zbuf = (float*)ws;                 // B*T
        float* lb   = zbuf + BT;                  // B
        int nrows = B * T;
        softmax_z_kernel<<<(nrows + 3) / 4, 256, 0, stream>>>(pred, zbuf, nrows);
        ctc_scan_kernel<<<B, 64, 0, stream>>>(pred, plen, gts, glen, zbuf, lb, T, S);
        ctc_reduce_kernel<<<1, 64, 0, stream>>>(lb, out, B);
    }
}